// Round 1
// baseline (8080.309 us; speedup 1.0000x reference)
//
#include <hip/hip_runtime.h>
#include <math.h>

// SNN: 5 LIF layers, B=2048, dims 100->128->256->512->1024->784, 25 steps.
// Round 1: correctness-first fp32. Fused GEMM(relu(h@W^T+b)) + LIF epilogue.
// LIF update uses __f*_rn intrinsics to forbid fma contraction so the op
// order matches the numpy reference (beta*mem, +cur, -reset as 3 roundings).

#define BM 64
#define BN 64
#define BK 16
#define TM 4
#define TN 4

// MODE: 0 = mid layer (gemm + LIF, store spikes to spk)
//       1 = last layer (gemm + LIF, store spikes + tanh(mem) to out)
//       2 = gemm+relu only (store cur to spk) -- used once for layer-1 cur
template <int MODE>
__global__ __launch_bounds__(256) void lif_layer_kernel(
    const float* __restrict__ h, const float* __restrict__ W,
    const float* __restrict__ bias, float* __restrict__ mem,
    float* __restrict__ spk, float* __restrict__ spk_rec,
    float* __restrict__ mem_rec, int N, int K) {
  __shared__ float As[BK][BM];
  __shared__ float Bs[BK][BN];

  const int t = threadIdx.x;
  const int tx = t & 15;   // n-direction
  const int ty = t >> 4;   // m-direction
  const int m0 = blockIdx.y * BM;
  const int n0 = blockIdx.x * BN;

  // cooperative-load indices: 256 threads, each loads 4 consecutive K elems
  const int lr = t >> 2;        // 0..63 row within tile
  const int lc = (t & 3) * 4;   // 0,4,8,12 col (k) within tile

  float acc[TM][TN];
#pragma unroll
  for (int i = 0; i < TM; ++i)
#pragma unroll
    for (int j = 0; j < TN; ++j) acc[i][j] = 0.0f;

  const int ktiles = (K + BK - 1) / BK;
  for (int kt = 0; kt < ktiles; ++kt) {
    const int kbase = kt * BK;
    {
      const float* src = h + (size_t)(m0 + lr) * K + kbase + lc;
#pragma unroll
      for (int j = 0; j < 4; ++j) {
        const int kg = kbase + lc + j;
        As[lc + j][lr] = (kg < K) ? src[j] : 0.0f;
      }
    }
    {
      const int nr = n0 + lr;
      const float* src = W + (size_t)nr * K + kbase + lc;
#pragma unroll
      for (int j = 0; j < 4; ++j) {
        const int kg = kbase + lc + j;
        Bs[lc + j][lr] = (nr < N && kg < K) ? src[j] : 0.0f;
      }
    }
    __syncthreads();
#pragma unroll
    for (int k = 0; k < BK; ++k) {
      float a[TM], bb[TN];
#pragma unroll
      for (int i = 0; i < TM; ++i) a[i] = As[k][ty * TM + i];
#pragma unroll
      for (int j = 0; j < TN; ++j) bb[j] = Bs[k][tx * TN + j];
#pragma unroll
      for (int i = 0; i < TM; ++i)
#pragma unroll
        for (int j = 0; j < TN; ++j) acc[i][j] = fmaf(a[i], bb[j], acc[i][j]);
    }
    __syncthreads();
  }

#pragma unroll
  for (int i = 0; i < TM; ++i) {
    const int m = m0 + ty * TM + i;
#pragma unroll
    for (int j = 0; j < TN; ++j) {
      const int n = n0 + tx * TN + j;
      if (n < N) {
        float cur = acc[i][j] + bias[n];
        cur = cur > 0.0f ? cur : 0.0f;
        const size_t idx = (size_t)m * N + n;
        if (MODE == 2) {
          spk[idx] = cur;
        } else {
          const float mo = mem[idx];
          const float reset = (mo - 1.0f > 0.0f) ? 1.0f : 0.0f;
          // match numpy op order: (beta*mem) + cur, then - reset
          float mn = __fmul_rn(0.95f, mo);
          mn = __fadd_rn(mn, cur);
          mn = __fsub_rn(mn, reset);
          mem[idx] = mn;
          const float s = (mn - 1.0f > 0.0f) ? 1.0f : 0.0f;
          if (MODE == 1) {
            spk_rec[idx] = s;
            mem_rec[idx] = tanhf(mn);
          } else {
            spk[idx] = s;
          }
        }
      }
    }
  }
}

// elementwise LIF for layer 1 (cur1 is constant across steps)
__global__ __launch_bounds__(256) void lif_elem_kernel(
    const float* __restrict__ cur, float* __restrict__ mem,
    float* __restrict__ spk, int n) {
  const int i = blockIdx.x * blockDim.x + threadIdx.x;
  if (i < n) {
    const float mo = mem[i];
    const float reset = (mo - 1.0f > 0.0f) ? 1.0f : 0.0f;
    float mn = __fmul_rn(0.95f, mo);
    mn = __fadd_rn(mn, cur[i]);
    mn = __fsub_rn(mn, reset);
    mem[i] = mn;
    spk[i] = (mn - 1.0f > 0.0f) ? 1.0f : 0.0f;
  }
}

extern "C" void kernel_launch(void* const* d_in, const int* in_sizes, int n_in,
                              void* d_out, int out_size, void* d_ws,
                              size_t ws_size, hipStream_t stream) {
  const float* x = (const float*)d_in[0];
  const float* W[5];
  const float* bi[5];
  for (int i = 0; i < 5; ++i) {
    W[i] = (const float*)d_in[1 + 2 * i];
    bi[i] = (const float*)d_in[2 + 2 * i];
  }

  const int B = 2048;
  const int Ns[5] = {128, 256, 512, 1024, 784};

  float* ws = (float*)d_ws;
  float* mem[5];
  size_t off = 0;
  for (int i = 0; i < 5; ++i) {
    mem[i] = ws + off;
    off += (size_t)B * Ns[i];
  }
  const size_t memTotal = off;  // 5,537,792 floats
  float* cur1 = ws + off; off += (size_t)B * 128;
  float* s1 = ws + off;   off += (size_t)B * 128;
  float* s2 = ws + off;   off += (size_t)B * 256;
  float* s3 = ws + off;   off += (size_t)B * 512;
  float* s4 = ws + off;   off += (size_t)B * 1024;

  hipMemsetAsync(ws, 0, memTotal * sizeof(float), stream);

  float* outF = (float*)d_out;
  float* spk_rec = outF;
  float* mem_rec = outF + (size_t)25 * B * 784;

  const dim3 blk(256);
  // cur1 = relu(x @ W1^T + b1), computed once (x identical every step)
  lif_layer_kernel<2><<<dim3(2, B / 64), blk, 0, stream>>>(
      x, W[0], bi[0], nullptr, cur1, nullptr, nullptr, 128, 100);

  for (int step = 0; step < 25; ++step) {
    const int nElem = B * 128;
    lif_elem_kernel<<<(nElem + 255) / 256, 256, 0, stream>>>(cur1, mem[0], s1,
                                                             nElem);
    lif_layer_kernel<0><<<dim3(4, B / 64), blk, 0, stream>>>(
        s1, W[1], bi[1], mem[1], s2, nullptr, nullptr, 256, 128);
    lif_layer_kernel<0><<<dim3(8, B / 64), blk, 0, stream>>>(
        s2, W[2], bi[2], mem[2], s3, nullptr, nullptr, 512, 256);
    lif_layer_kernel<0><<<dim3(16, B / 64), blk, 0, stream>>>(
        s3, W[3], bi[3], mem[3], s4, nullptr, nullptr, 1024, 512);
    lif_layer_kernel<1><<<dim3(13, B / 64), blk, 0, stream>>>(
        s4, W[4], bi[4], mem[4], nullptr, spk_rec + (size_t)step * B * 784,
        mem_rec + (size_t)step * B * 784, 784, 1024);
  }
}

// Round 3
// 5053.781 us; speedup vs baseline: 1.5989x; 1.5989x over previous
//
#include <hip/hip_runtime.h>
#include <math.h>

// SNN: 5 LIF layers, B=2048, dims 100->128->256->512->1024->784, 25 steps.
// Round 3: fast fp32 VALU GEMM (128x64 tile, 8x4 micro) with the EXACT same
// per-output accumulation order as the round-1 kernel that passed (ascending-k
// single fmaf chain, bias added once at the end, __f*_rn LIF ops). This makes
// the outputs bit-identical to round 1 -- the np reference's fp32 sgemm is
// k-sequential, and matching that rounding pattern is what keeps all ~138M
// Heaviside spike decisions from flipping. MFMA/bf16 paths change the
// summation structure and flipped spikes (round 2); fp32-sequential is the
// numerically-safe lane.

#define B_TOTAL 2048

// ---------- fp32 64x64 GEMM + relu (layer-1 current, runs once) ------------
// Round-1 verbatim arithmetic (BK=16 ascending, zero-fill tail of K=100:
// fmaf(0,0,acc) is exact identity so the chain matches a dense k-sweep).
__global__ __launch_bounds__(256) void gemm_relu_f32_kernel(
    const float* __restrict__ h, const float* __restrict__ W,
    const float* __restrict__ bias, float* __restrict__ out, int N, int K) {
  __shared__ float As[16][64];
  __shared__ float Bs[16][64];

  const int t = threadIdx.x;
  const int tx = t & 15;
  const int ty = t >> 4;
  const int m0 = blockIdx.y * 64;
  const int n0 = blockIdx.x * 64;
  const int lr = t >> 2;
  const int lc = (t & 3) * 4;

  float acc[4][4];
#pragma unroll
  for (int i = 0; i < 4; ++i)
#pragma unroll
    for (int j = 0; j < 4; ++j) acc[i][j] = 0.0f;

  const int ktiles = (K + 15) / 16;
  for (int kt = 0; kt < ktiles; ++kt) {
    const int kbase = kt * 16;
    {
      const float* src = h + (size_t)(m0 + lr) * K + kbase + lc;
#pragma unroll
      for (int j = 0; j < 4; ++j) {
        const int kg = kbase + lc + j;
        As[lc + j][lr] = (kg < K) ? src[j] : 0.0f;
      }
    }
    {
      const int nr = n0 + lr;
      const float* src = W + (size_t)nr * K + kbase + lc;
#pragma unroll
      for (int j = 0; j < 4; ++j) {
        const int kg = kbase + lc + j;
        Bs[lc + j][lr] = (nr < N && kg < K) ? src[j] : 0.0f;
      }
    }
    __syncthreads();
#pragma unroll
    for (int k = 0; k < 16; ++k) {
      float a[4], bb[4];
#pragma unroll
      for (int i = 0; i < 4; ++i) a[i] = As[k][ty * 4 + i];
#pragma unroll
      for (int j = 0; j < 4; ++j) bb[j] = Bs[k][tx * 4 + j];
#pragma unroll
      for (int i = 0; i < 4; ++i)
#pragma unroll
        for (int j = 0; j < 4; ++j) acc[i][j] = fmaf(a[i], bb[j], acc[i][j]);
    }
    __syncthreads();
  }

#pragma unroll
  for (int i = 0; i < 4; ++i) {
    const int m = m0 + ty * 4 + i;
#pragma unroll
    for (int j = 0; j < 4; ++j) {
      const int n = n0 + tx * 4 + j;
      if (n < N) {
        float cur = acc[i][j] + bias[n];
        out[(size_t)m * N + n] = cur > 0.0f ? cur : 0.0f;
      }
    }
  }
}

// ---------- elementwise LIF for layer 1 (cur constant across steps) --------
__global__ __launch_bounds__(256) void lif_elem_kernel(
    const float* __restrict__ cur, float* __restrict__ mem,
    float* __restrict__ spk, int n) {
  const int i = blockIdx.x * blockDim.x + threadIdx.x;
  if (i < n) {
    const float mo = mem[i];
    const float reset = (mo - 1.0f > 0.0f) ? 1.0f : 0.0f;
    float mn = __fmul_rn(0.95f, mo);
    mn = __fadd_rn(mn, cur[i]);
    mn = __fsub_rn(mn, reset);
    mem[i] = mn;
    spk[i] = (mn - 1.0f > 0.0f) ? 1.0f : 0.0f;
  }
}

// ---------- fast fp32 GEMM + LIF: 128x64 tile, 8x4 micro-tile ---------------
// Same k-ascending fmaf chain per output as gemm_relu_f32_kernel (K is a
// multiple of 32 for layers 2-5, so no tail handling => identical op order).
// MODE 0: mid layer -> write spikes (f32) to spk
// MODE 1: last layer -> write spikes to spk_rec, tanhf(mem) to mem_rec
template <int MODE>
__global__ __launch_bounds__(256) void fgemm_lif_kernel(
    const float* __restrict__ h, const float* __restrict__ W,
    const float* __restrict__ bias, float* __restrict__ mem,
    float* __restrict__ spk, float* __restrict__ spk_rec,
    float* __restrict__ mem_rec, int N, int K) {
  __shared__ float As[32][128];  // [k][m]
  __shared__ float Ws[32][64];   // [k][n]

  const int t = threadIdx.x;
  const int m0 = blockIdx.y * 128;
  const int n0 = blockIdx.x * 64;
  const int tn = t & 15;   // n group: 16 groups x 4 = 64
  const int tm = t >> 4;   // m group: 16 groups x 8 = 128

  // A staging: row ar = t&127, cols ac..ac+15 (2 half-rows per row)
  const int ar = t & 127;
  const int ac = (t >> 7) * 16;
  // W staging: row wr = t&63, cols wc..wc+7 (4 quarter-rows per row)
  const int wr = t & 63;
  const int wc = (t >> 6) * 8;

  float acc[8][4];
#pragma unroll
  for (int i = 0; i < 8; ++i)
#pragma unroll
    for (int j = 0; j < 4; ++j) acc[i][j] = 0.0f;

  for (int kb = 0; kb < K; kb += 32) {
    {
      const float* srcA = h + (size_t)(m0 + ar) * K + kb + ac;
#pragma unroll
      for (int u = 0; u < 4; ++u) {
        const float4 v = *(const float4*)(srcA + u * 4);
        As[ac + u * 4 + 0][ar] = v.x;
        As[ac + u * 4 + 1][ar] = v.y;
        As[ac + u * 4 + 2][ar] = v.z;
        As[ac + u * 4 + 3][ar] = v.w;
      }
    }
    {
      const int nr = n0 + wr;
      const float* srcW = W + (size_t)nr * K + kb + wc;
#pragma unroll
      for (int u = 0; u < 2; ++u) {
        float4 v = {0.0f, 0.0f, 0.0f, 0.0f};
        if (nr < N) v = *(const float4*)(srcW + u * 4);
        Ws[wc + u * 4 + 0][wr] = v.x;
        Ws[wc + u * 4 + 1][wr] = v.y;
        Ws[wc + u * 4 + 2][wr] = v.z;
        Ws[wc + u * 4 + 3][wr] = v.w;
      }
    }
    __syncthreads();
#pragma unroll
    for (int k = 0; k < 32; ++k) {
      float a[8], w[4];
#pragma unroll
      for (int i = 0; i < 8; ++i) a[i] = As[k][tm * 8 + i];
#pragma unroll
      for (int j = 0; j < 4; ++j) w[j] = Ws[k][tn * 4 + j];
#pragma unroll
      for (int i = 0; i < 8; ++i)
#pragma unroll
        for (int j = 0; j < 4; ++j) acc[i][j] = fmaf(a[i], w[j], acc[i][j]);
    }
    __syncthreads();
  }

  // ---- fused LIF epilogue (float4 over the 4 n's per thread) ----
  const int n = n0 + tn * 4;
  if (n < N) {  // N % 4 == 0 for all layers, so n < N covers the whole quad
    const float4 bb = *(const float4*)(bias + n);
#pragma unroll
    for (int i = 0; i < 8; ++i) {
      const int m = m0 + tm * 8 + i;
      const size_t idx = (size_t)m * N + n;
      const float4 mo = *(const float4*)(mem + idx);
      float4 mv, sv, tv;
      const float bias_a[4] = {bb.x, bb.y, bb.z, bb.w};
      const float mo_a[4] = {mo.x, mo.y, mo.z, mo.w};
      float mn_a[4], s_a[4], t_a[4];
#pragma unroll
      for (int j = 0; j < 4; ++j) {
        float cur = acc[i][j] + bias_a[j];
        cur = cur > 0.0f ? cur : 0.0f;
        const float reset = (mo_a[j] - 1.0f > 0.0f) ? 1.0f : 0.0f;
        float mn = __fmul_rn(0.95f, mo_a[j]);
        mn = __fadd_rn(mn, cur);
        mn = __fsub_rn(mn, reset);
        mn_a[j] = mn;
        s_a[j] = (mn - 1.0f > 0.0f) ? 1.0f : 0.0f;
        if (MODE == 1) t_a[j] = tanhf(mn);
      }
      mv.x = mn_a[0]; mv.y = mn_a[1]; mv.z = mn_a[2]; mv.w = mn_a[3];
      sv.x = s_a[0];  sv.y = s_a[1];  sv.z = s_a[2];  sv.w = s_a[3];
      *(float4*)(mem + idx) = mv;
      if (MODE == 1) {
        tv.x = t_a[0]; tv.y = t_a[1]; tv.z = t_a[2]; tv.w = t_a[3];
        *(float4*)(spk_rec + idx) = sv;
        *(float4*)(mem_rec + idx) = tv;
      } else {
        *(float4*)(spk + idx) = sv;
      }
    }
  }
}

// ---------------------------------------------------------------------------
extern "C" void kernel_launch(void* const* d_in, const int* in_sizes, int n_in,
                              void* d_out, int out_size, void* d_ws,
                              size_t ws_size, hipStream_t stream) {
  const float* x = (const float*)d_in[0];
  const float* W[5];
  const float* bi[5];
  for (int i = 0; i < 5; ++i) {
    W[i] = (const float*)d_in[1 + 2 * i];
    bi[i] = (const float*)d_in[2 + 2 * i];
  }

  const int B = B_TOTAL;
  const int Ns[5] = {128, 256, 512, 1024, 784};
  const int Ks[5] = {100, 128, 256, 512, 1024};

  float* ws = (float*)d_ws;
  float* mem[5];
  size_t off = 0;
  for (int i = 0; i < 5; ++i) {
    mem[i] = ws + off;
    off += (size_t)B * Ns[i];
  }
  const size_t memFloats = off;
  float* cur1 = ws + off; off += (size_t)B * 128;
  float* s1 = ws + off;   off += (size_t)B * 128;
  float* s2 = ws + off;   off += (size_t)B * 256;
  float* s3 = ws + off;   off += (size_t)B * 512;
  float* s4 = ws + off;   off += (size_t)B * 1024;

  hipMemsetAsync(ws, 0, memFloats * sizeof(float), stream);

  float* outF = (float*)d_out;
  float* spk_rec = outF;
  float* mem_rec = outF + (size_t)25 * B * 784;

  // layer-1 current: relu(x @ W1^T + b1), computed once (x is step-invariant)
  gemm_relu_f32_kernel<<<dim3(2, B / 64), 256, 0, stream>>>(x, W[0], bi[0],
                                                            cur1, 128, 100);

  const float* sin_[5] = {nullptr, s1, s2, s3, s4};
  float* sout[5] = {s1, s2, s3, s4, nullptr};

  for (int step = 0; step < 25; ++step) {
    const int nElem = B * 128;
    lif_elem_kernel<<<(nElem + 255) / 256, 256, 0, stream>>>(cur1, mem[0], s1,
                                                             nElem);
    for (int l = 1; l < 4; ++l) {
      fgemm_lif_kernel<0><<<dim3((Ns[l] + 63) / 64, B / 128), 256, 0,
                            stream>>>(sin_[l], W[l], bi[l], mem[l], sout[l],
                                      nullptr, nullptr, Ns[l], Ks[l]);
    }
    fgemm_lif_kernel<1><<<dim3((784 + 63) / 64, B / 128), 256, 0, stream>>>(
        s4, W[4], bi[4], mem[4], nullptr, spk_rec + (size_t)step * B * 784,
        mem_rec + (size_t)step * B * 784, 784, 1024);
  }
}

// Round 4
// 4497.808 us; speedup vs baseline: 1.7965x; 1.1236x over previous
//
#include <hip/hip_runtime.h>
#include <hip/hip_bf16.h>
#include <math.h>

// SNN: 5 LIF layers, B=2048, dims 100->128->256->512->1024->784, 25 steps.
// Round 4: bf16 MFMA GEMM with TRIPLE-split weights. Spikes are {0,1} (exact
// in bf16) so every MFMA product is exact; w = hi+mid+lo (3x bf16, Dekker
// splits, 24 mantissa bits) makes the weight decomposition exact too. The
// only deviation vs the np reference is fp32 summation ORDER -- the same
// error class as round 3's VALU kernel, which passed. (Round 2's 2-way split
// left a 2^-16 residual -> ~1e-5 error windows -> spike flips. Removed.)
// LIF epilogue keeps the __f*_rn op chain and tanhf from the passing rounds.

typedef __hip_bfloat16 bf16;
typedef __attribute__((ext_vector_type(8))) short short8;
typedef __attribute__((ext_vector_type(4))) float f32x4;

#define B_TOTAL 2048

// ---------- fp32 64x64 GEMM + relu (layer-1 current, runs once) ------------
__global__ __launch_bounds__(256) void gemm_relu_f32_kernel(
    const float* __restrict__ h, const float* __restrict__ W,
    const float* __restrict__ bias, float* __restrict__ out, int N, int K) {
  __shared__ float As[16][64];
  __shared__ float Bs[16][64];

  const int t = threadIdx.x;
  const int tx = t & 15;
  const int ty = t >> 4;
  const int m0 = blockIdx.y * 64;
  const int n0 = blockIdx.x * 64;
  const int lr = t >> 2;
  const int lc = (t & 3) * 4;

  float acc[4][4];
#pragma unroll
  for (int i = 0; i < 4; ++i)
#pragma unroll
    for (int j = 0; j < 4; ++j) acc[i][j] = 0.0f;

  const int ktiles = (K + 15) / 16;
  for (int kt = 0; kt < ktiles; ++kt) {
    const int kbase = kt * 16;
    {
      const float* src = h + (size_t)(m0 + lr) * K + kbase + lc;
#pragma unroll
      for (int j = 0; j < 4; ++j) {
        const int kg = kbase + lc + j;
        As[lc + j][lr] = (kg < K) ? src[j] : 0.0f;
      }
    }
    {
      const int nr = n0 + lr;
      const float* src = W + (size_t)nr * K + kbase + lc;
#pragma unroll
      for (int j = 0; j < 4; ++j) {
        const int kg = kbase + lc + j;
        Bs[lc + j][lr] = (nr < N && kg < K) ? src[j] : 0.0f;
      }
    }
    __syncthreads();
#pragma unroll
    for (int k = 0; k < 16; ++k) {
      float a[4], bb[4];
#pragma unroll
      for (int i = 0; i < 4; ++i) a[i] = As[k][ty * 4 + i];
#pragma unroll
      for (int j = 0; j < 4; ++j) bb[j] = Bs[k][tx * 4 + j];
#pragma unroll
      for (int i = 0; i < 4; ++i)
#pragma unroll
        for (int j = 0; j < 4; ++j) acc[i][j] = fmaf(a[i], bb[j], acc[i][j]);
    }
    __syncthreads();
  }

#pragma unroll
  for (int i = 0; i < 4; ++i) {
    const int m = m0 + ty * 4 + i;
#pragma unroll
    for (int j = 0; j < 4; ++j) {
      const int n = n0 + tx * 4 + j;
      if (n < N) {
        float cur = acc[i][j] + bias[n];
        out[(size_t)m * N + n] = cur > 0.0f ? cur : 0.0f;
      }
    }
  }
}

// ---------- triple split: W fp32 [N,K] -> Wc bf16 [N, 3K] = [hi|mid|lo] ----
// Dekker-exact: each residual subtraction is exact in fp32; hi+mid+lo
// reconstructs w to within < 2^-24 relative (usually exactly).
__global__ __launch_bounds__(256) void split3_kernel(
    const float* __restrict__ W, bf16* __restrict__ Wc, int total, int K) {
  const int idx = blockIdx.x * 256 + threadIdx.x;
  if (idx < total) {
    const int n = idx / K;
    const int k = idx - n * K;
    const float w = W[idx];
    const bf16 hi = __float2bfloat16(w);
    const float r1 = w - __bfloat162float(hi);
    const bf16 mid = __float2bfloat16(r1);
    const float r2 = r1 - __bfloat162float(mid);
    const bf16 lo = __float2bfloat16(r2);
    const size_t base = (size_t)n * 3 * K + k;
    Wc[base] = hi;
    Wc[base + K] = mid;
    Wc[base + 2 * K] = lo;
  }
}

// ---------- elementwise LIF for layer 1 (cur constant across steps) --------
__global__ __launch_bounds__(256) void lif_elem_kernel(
    const float* __restrict__ cur, float* __restrict__ mem,
    bf16* __restrict__ spk, int n) {
  const int i = blockIdx.x * blockDim.x + threadIdx.x;
  if (i < n) {
    const float mo = mem[i];
    const float reset = (mo - 1.0f > 0.0f) ? 1.0f : 0.0f;
    float mn = __fmul_rn(0.95f, mo);
    mn = __fadd_rn(mn, cur[i]);
    mn = __fsub_rn(mn, reset);
    mem[i] = mn;
    spk[i] = __float2bfloat16((mn - 1.0f > 0.0f) ? 1.0f : 0.0f);
  }
}

// ---------- bf16 MFMA GEMM (128x64 tile, BK=64) + LIF epilogue -------------
// C[2048, N] = A[2048, K] @ Wc^T, Wc = [N, 3K] = [hi|mid|lo]; the k loop runs
// over K3 = 3K and the A k-index wraps mod K so each split part multiplies
// the same spikes. 4 waves in a 2x2 grid; each wave owns a 64x32 subtile as
// 4x2 fragments of mfma_f32_16x16x32_bf16.
// Verified layouts (m89/m91/m92): A-frag  A[m = lane&15][k = (lane>>4)*8+j],
// C/D frag: col = lane&15, row = (lane>>4)*4 + reg.
// MODE 0: mid layer -> spikes (bf16) to spk
// MODE 1: last layer -> spikes (f32) to spk_rec, tanhf(mem) to mem_rec
template <int MODE>
__global__ __launch_bounds__(256) void mfma3_lif_kernel(
    const bf16* __restrict__ A, const bf16* __restrict__ Wc,
    const float* __restrict__ bias, float* __restrict__ mem,
    bf16* __restrict__ spk, float* __restrict__ spk_rec,
    float* __restrict__ mem_rec, int N, int K, int K3) {
  __shared__ bf16 As[128][72];  // +8 pad: 2-way bank aliasing only (free)
  __shared__ bf16 Bs[64][72];

  const int t = threadIdx.x;
  const int lane = t & 63;
  const int w = t >> 6;     // wave 0..3
  const int wm = w >> 1;    // wave m (0..1): rows wm*64..+64
  const int wn = w & 1;     // wave n (0..1): cols wn*32..+32
  const int m0 = blockIdx.y * 128;
  const int n0 = blockIdx.x * 64;

  // staging: thread covers rows (t>>3) + 32*i, 16B chunk (t&7)*8 within BK=64
  const int lrow = t >> 3;       // 0..31
  const int lk = (t & 7) * 8;    // 0,8,...,56

  f32x4 acc[4][2];
#pragma unroll
  for (int i = 0; i < 4; ++i)
#pragma unroll
    for (int j = 0; j < 2; ++j) acc[i][j] = 0.0f;

  for (int kt = 0; kt < K3; kt += 64) {
    int ka = kt;  // A k-index wraps mod K (K3 = 3K, K multiple of 64)
    if (ka >= K) ka -= K;
    if (ka >= K) ka -= K;
    {
      const bf16* srcA = A + (size_t)(m0 + lrow) * K + ka + lk;
#pragma unroll
      for (int i = 0; i < 4; ++i)
        *(short8*)(&As[lrow + 32 * i][lk]) =
            *(const short8*)(srcA + (size_t)32 * i * K);
    }
    {
#pragma unroll
      for (int i = 0; i < 2; ++i) {
        const int r = lrow + 32 * i;
        short8 vb = {};
        if (n0 + r < N)
          vb = *(const short8*)(Wc + (size_t)(n0 + r) * K3 + kt + lk);
        *(short8*)(&Bs[r][lk]) = vb;
      }
    }
    __syncthreads();
#pragma unroll
    for (int ks = 0; ks < 64; ks += 32) {
      const int kb = ks + (lane >> 4) * 8;
      short8 af[4], bfr[2];
#pragma unroll
      for (int i = 0; i < 4; ++i)
        af[i] = *(const short8*)(&As[wm * 64 + i * 16 + (lane & 15)][kb]);
#pragma unroll
      for (int j = 0; j < 2; ++j)
        bfr[j] = *(const short8*)(&Bs[wn * 32 + j * 16 + (lane & 15)][kb]);
#pragma unroll
      for (int i = 0; i < 4; ++i)
#pragma unroll
        for (int j = 0; j < 2; ++j)
          acc[i][j] = __builtin_amdgcn_mfma_f32_16x16x32_bf16(
              af[i], bfr[j], acc[i][j], 0, 0, 0);
    }
    __syncthreads();
  }

  // epilogue: C/D mapping col=lane&15, row=(lane>>4)*4+reg
  const int col = lane & 15;
  const int rbase = (lane >> 4) * 4;
#pragma unroll
  for (int i = 0; i < 4; ++i) {
#pragma unroll
    for (int r = 0; r < 4; ++r) {
      const int m = m0 + wm * 64 + i * 16 + rbase + r;
#pragma unroll
      for (int j = 0; j < 2; ++j) {
        const int n = n0 + wn * 32 + j * 16 + col;
        if (n < N) {
          float cur = acc[i][j][r] + bias[n];
          cur = cur > 0.0f ? cur : 0.0f;
          const size_t idx = (size_t)m * N + n;
          const float mo = mem[idx];
          const float reset = (mo - 1.0f > 0.0f) ? 1.0f : 0.0f;
          float mn = __fmul_rn(0.95f, mo);
          mn = __fadd_rn(mn, cur);
          mn = __fsub_rn(mn, reset);
          mem[idx] = mn;
          const float s = (mn - 1.0f > 0.0f) ? 1.0f : 0.0f;
          if (MODE == 1) {
            spk_rec[idx] = s;
            mem_rec[idx] = tanhf(mn);
          } else {
            spk[idx] = __float2bfloat16(s);
          }
        }
      }
    }
  }
}

// ---------------------------------------------------------------------------
extern "C" void kernel_launch(void* const* d_in, const int* in_sizes, int n_in,
                              void* d_out, int out_size, void* d_ws,
                              size_t ws_size, hipStream_t stream) {
  const float* x = (const float*)d_in[0];
  const float* W[5];
  const float* bi[5];
  for (int i = 0; i < 5; ++i) {
    W[i] = (const float*)d_in[1 + 2 * i];
    bi[i] = (const float*)d_in[2 + 2 * i];
  }

  const int B = B_TOTAL;
  const int Ns[5] = {128, 256, 512, 1024, 784};
  const int Ks[5] = {100, 128, 256, 512, 1024};

  char* ws = (char*)d_ws;
  size_t off = 0;
  auto alloc = [&](size_t bytes) {
    void* p = ws + off;
    off = (off + bytes + 255) & ~(size_t)255;
    return p;
  };

  float* mem[5];
  for (int i = 0; i < 5; ++i) mem[i] = (float*)alloc((size_t)B * Ns[i] * 4);
  const size_t memBytes = off;
  float* cur1 = (float*)alloc((size_t)B * 128 * 4);
  bf16* s1 = (bf16*)alloc((size_t)B * 128 * 2);
  bf16* s2 = (bf16*)alloc((size_t)B * 256 * 2);
  bf16* s3 = (bf16*)alloc((size_t)B * 512 * 2);
  bf16* s4 = (bf16*)alloc((size_t)B * 1024 * 2);
  bf16* Wc[5];
  for (int i = 1; i < 5; ++i)
    Wc[i] = (bf16*)alloc((size_t)Ns[i] * Ks[i] * 3 * 2);

  hipMemsetAsync(d_ws, 0, memBytes, stream);

  float* outF = (float*)d_out;
  float* spk_rec = outF;
  float* mem_rec = outF + (size_t)25 * B * 784;

  // triple-split weights for layers 2..5
  for (int i = 1; i < 5; ++i) {
    const int total = Ns[i] * Ks[i];
    split3_kernel<<<(total + 255) / 256, 256, 0, stream>>>(W[i], Wc[i], total,
                                                           Ks[i]);
  }

  // layer-1 current: relu(x @ W1^T + b1), computed once (x is step-invariant)
  gemm_relu_f32_kernel<<<dim3(2, B / 64), 256, 0, stream>>>(x, W[0], bi[0],
                                                            cur1, 128, 100);

  const bf16* sin_[5] = {nullptr, s1, s2, s3, s4};
  bf16* sout[5] = {s1, s2, s3, s4, nullptr};

  for (int step = 0; step < 25; ++step) {
    const int nElem = B * 128;
    lif_elem_kernel<<<(nElem + 255) / 256, 256, 0, stream>>>(cur1, mem[0], s1,
                                                             nElem);
    for (int l = 1; l < 4; ++l) {
      mfma3_lif_kernel<0><<<dim3((Ns[l] + 63) / 64, B / 128), 256, 0,
                            stream>>>(sin_[l], Wc[l], bi[l], mem[l], sout[l],
                                      nullptr, nullptr, Ns[l], Ks[l],
                                      3 * Ks[l]);
    }
    mfma3_lif_kernel<1><<<dim3((784 + 63) / 64, B / 128), 256, 0, stream>>>(
        s4, Wc[4], bi[4], mem[4], nullptr, spk_rec + (size_t)step * B * 784,
        mem_rec + (size_t)step * B * 784, 784, 1024, 3072);
  }
}

// Round 5
// 2582.241 us; speedup vs baseline: 3.1292x; 1.7418x over previous
//
#include <hip/hip_runtime.h>
#include <hip/hip_bf16.h>
#include <math.h>

// SNN: 5 LIF layers, B=2048, dims 100->128->256->512->1024->784, 25 steps.
// Round 5: DIAGONAL FUSION. Layer l @ step t depends only on layer l-1 @ t
// and its own mem @ t-1, so the anti-diagonal {lif1@d, L2@d-1, L3@d-2,
// L4@d-3, L5@d-4} is mutually independent -> one fused kernel per diagonal
// (29 total). This lifts occupancy from <=1 block/CU (round 4's 4x-loss) to
// ~3.5 blocks/CU and cuts launches 155->34. GEMM body and all arithmetic are
// round-4 verbatim (triple-split bf16 MFMA, exact decomposition; fp32
// reorder-only error class) -> bit-identical outputs to round 4.

typedef __hip_bfloat16 bf16;
typedef __attribute__((ext_vector_type(8))) short short8;
typedef __attribute__((ext_vector_type(4))) float f32x4;

#define B_TOTAL 2048

// ---------- fp32 64x64 GEMM + relu (layer-1 current, runs once) ------------
__global__ __launch_bounds__(256) void gemm_relu_f32_kernel(
    const float* __restrict__ h, const float* __restrict__ W,
    const float* __restrict__ bias, float* __restrict__ out, int N, int K) {
  __shared__ float As[16][64];
  __shared__ float Bs[16][64];

  const int t = threadIdx.x;
  const int tx = t & 15;
  const int ty = t >> 4;
  const int m0 = blockIdx.y * 64;
  const int n0 = blockIdx.x * 64;
  const int lr = t >> 2;
  const int lc = (t & 3) * 4;

  float acc[4][4];
#pragma unroll
  for (int i = 0; i < 4; ++i)
#pragma unroll
    for (int j = 0; j < 4; ++j) acc[i][j] = 0.0f;

  const int ktiles = (K + 15) / 16;
  for (int kt = 0; kt < ktiles; ++kt) {
    const int kbase = kt * 16;
    {
      const float* src = h + (size_t)(m0 + lr) * K + kbase + lc;
#pragma unroll
      for (int j = 0; j < 4; ++j) {
        const int kg = kbase + lc + j;
        As[lc + j][lr] = (kg < K) ? src[j] : 0.0f;
      }
    }
    {
      const int nr = n0 + lr;
      const float* src = W + (size_t)nr * K + kbase + lc;
#pragma unroll
      for (int j = 0; j < 4; ++j) {
        const int kg = kbase + lc + j;
        Bs[lc + j][lr] = (nr < N && kg < K) ? src[j] : 0.0f;
      }
    }
    __syncthreads();
#pragma unroll
    for (int k = 0; k < 16; ++k) {
      float a[4], bb[4];
#pragma unroll
      for (int i = 0; i < 4; ++i) a[i] = As[k][ty * 4 + i];
#pragma unroll
      for (int j = 0; j < 4; ++j) bb[j] = Bs[k][tx * 4 + j];
#pragma unroll
      for (int i = 0; i < 4; ++i)
#pragma unroll
        for (int j = 0; j < 4; ++j) acc[i][j] = fmaf(a[i], bb[j], acc[i][j]);
    }
    __syncthreads();
  }

#pragma unroll
  for (int i = 0; i < 4; ++i) {
    const int m = m0 + ty * 4 + i;
#pragma unroll
    for (int j = 0; j < 4; ++j) {
      const int n = n0 + tx * 4 + j;
      if (n < N) {
        float cur = acc[i][j] + bias[n];
        out[(size_t)m * N + n] = cur > 0.0f ? cur : 0.0f;
      }
    }
  }
}

// ---------- triple split: W fp32 [N,K] -> Wc bf16 [N, 3K] = [hi|mid|lo] ----
__global__ __launch_bounds__(256) void split3_kernel(
    const float* __restrict__ W, bf16* __restrict__ Wc, int total, int K) {
  const int idx = blockIdx.x * 256 + threadIdx.x;
  if (idx < total) {
    const int n = idx / K;
    const int k = idx - n * K;
    const float w = W[idx];
    const bf16 hi = __float2bfloat16(w);
    const float r1 = w - __bfloat162float(hi);
    const bf16 mid = __float2bfloat16(r1);
    const float r2 = r1 - __bfloat162float(mid);
    const bf16 lo = __float2bfloat16(r2);
    const size_t base = (size_t)n * 3 * K + k;
    Wc[base] = hi;
    Wc[base + K] = mid;
    Wc[base + 2 * K] = lo;
  }
}

// ---------- fused diagonal kernel ------------------------------------------
// Block ranges (longest task first so it's dispatched earliest):
//   L5 gemm (step d-4): 208 blocks   active d in [4,28]
//   L4 gemm (step d-3): 256 blocks   active d in [3,27]
//   L3 gemm (step d-2): 128 blocks   active d in [2,26]
//   L2 gemm (step d-1):  64 blocks   active d in [1,25]
//   lif1    (step d  ): 256 blocks   active d in [0,24]
// Spike buffers are double-buffered: producers write parity p=d&1, consumers
// read parity p^1 (written at diagonal d-1).
__global__ __launch_bounds__(256) void diag_kernel(
    int d,
    // lif1
    const float* __restrict__ cur1, float* __restrict__ mem1,
    bf16* __restrict__ s1_out,
    // L2
    const bf16* __restrict__ s1_in, const bf16* __restrict__ Wc2,
    const float* __restrict__ b2, float* __restrict__ mem2,
    bf16* __restrict__ s2_out,
    // L3
    const bf16* __restrict__ s2_in, const bf16* __restrict__ Wc3,
    const float* __restrict__ b3, float* __restrict__ mem3,
    bf16* __restrict__ s3_out,
    // L4
    const bf16* __restrict__ s3_in, const bf16* __restrict__ Wc4,
    const float* __restrict__ b4, float* __restrict__ mem4,
    bf16* __restrict__ s4_out,
    // L5
    const bf16* __restrict__ s4_in, const bf16* __restrict__ Wc5,
    const float* __restrict__ b5, float* __restrict__ mem5,
    float* __restrict__ sr, float* __restrict__ mr) {
  __shared__ bf16 As[128][72];  // +8 pad: 2-way bank aliasing only (free)
  __shared__ bf16 Bs[64][72];

  const int n5 = (d >= 4) ? 208 : 0;               // d <= 28 by construction
  const int n4 = (d >= 3 && d <= 27) ? 256 : 0;
  const int n3 = (d >= 2 && d <= 26) ? 128 : 0;
  const int n2 = (d >= 1 && d <= 25) ? 64 : 0;

  int b = blockIdx.x;
  const bf16* A;
  const bf16* Wc;
  const float* bias;
  float* mem;
  bf16* spk = nullptr;
  int N, K, nbx, mode, lb;

  if (b < n5) {
    lb = b; A = s4_in; Wc = Wc5; bias = b5; mem = mem5;
    N = 784; K = 1024; nbx = 13; mode = 1;
  } else if ((b -= n5) < n4) {
    lb = b; A = s3_in; Wc = Wc4; bias = b4; mem = mem4; spk = s4_out;
    N = 1024; K = 512; nbx = 16; mode = 0;
  } else if ((b -= n4) < n3) {
    lb = b; A = s2_in; Wc = Wc3; bias = b3; mem = mem3; spk = s3_out;
    N = 512; K = 256; nbx = 8; mode = 0;
  } else if ((b -= n3) < n2) {
    lb = b; A = s1_in; Wc = Wc2; bias = b2; mem = mem2; spk = s2_out;
    N = 256; K = 128; nbx = 4; mode = 0;
  } else {
    // ---- lif1 task: 256 blocks x 256 threads x 4 elems = 2048*128 ----
    lb = b - n2;
    const int i0 = (lb * 256 + (int)threadIdx.x) * 4;
    const float4 c = *(const float4*)(cur1 + i0);
    const float4 mo4 = *(const float4*)(mem1 + i0);
    const float c_a[4] = {c.x, c.y, c.z, c.w};
    const float mo_a[4] = {mo4.x, mo4.y, mo4.z, mo4.w};
    float mn_a[4];
#pragma unroll
    for (int j = 0; j < 4; ++j) {
      const float mo = mo_a[j];
      const float reset = (mo - 1.0f > 0.0f) ? 1.0f : 0.0f;
      float mn = __fmul_rn(0.95f, mo);
      mn = __fadd_rn(mn, c_a[j]);
      mn = __fsub_rn(mn, reset);
      mn_a[j] = mn;
      s1_out[i0 + j] = __float2bfloat16((mn - 1.0f > 0.0f) ? 1.0f : 0.0f);
    }
    float4 mv;
    mv.x = mn_a[0]; mv.y = mn_a[1]; mv.z = mn_a[2]; mv.w = mn_a[3];
    *(float4*)(mem1 + i0) = mv;
    return;
  }

  // ---- GEMM + LIF task (round-4 body, runtime dims) ----
  const int K3 = 3 * K;
  const int t = threadIdx.x;
  const int lane = t & 63;
  const int w = t >> 6;
  const int wm = w >> 1;
  const int wn = w & 1;
  const int m0 = (lb / nbx) * 128;
  const int n0 = (lb % nbx) * 64;

  const int lrow = t >> 3;
  const int lk = (t & 7) * 8;

  f32x4 acc[4][2];
#pragma unroll
  for (int i = 0; i < 4; ++i)
#pragma unroll
    for (int j = 0; j < 2; ++j) acc[i][j] = 0.0f;

  for (int kt = 0; kt < K3; kt += 64) {
    int ka = kt;
    if (ka >= K) ka -= K;
    if (ka >= K) ka -= K;
    {
      const bf16* srcA = A + (size_t)(m0 + lrow) * K + ka + lk;
#pragma unroll
      for (int i = 0; i < 4; ++i)
        *(short8*)(&As[lrow + 32 * i][lk]) =
            *(const short8*)(srcA + (size_t)32 * i * K);
    }
    {
#pragma unroll
      for (int i = 0; i < 2; ++i) {
        const int r = lrow + 32 * i;
        short8 vb = {};
        if (n0 + r < N)
          vb = *(const short8*)(Wc + (size_t)(n0 + r) * K3 + kt + lk);
        *(short8*)(&Bs[r][lk]) = vb;
      }
    }
    __syncthreads();
#pragma unroll
    for (int ks = 0; ks < 64; ks += 32) {
      const int kb = ks + (lane >> 4) * 8;
      short8 af[4], bfr[2];
#pragma unroll
      for (int i = 0; i < 4; ++i)
        af[i] = *(const short8*)(&As[wm * 64 + i * 16 + (lane & 15)][kb]);
#pragma unroll
      for (int j = 0; j < 2; ++j)
        bfr[j] = *(const short8*)(&Bs[wn * 32 + j * 16 + (lane & 15)][kb]);
#pragma unroll
      for (int i = 0; i < 4; ++i)
#pragma unroll
        for (int j = 0; j < 2; ++j)
          acc[i][j] = __builtin_amdgcn_mfma_f32_16x16x32_bf16(
              af[i], bfr[j], acc[i][j], 0, 0, 0);
    }
    __syncthreads();
  }

  // epilogue: C/D mapping col=lane&15, row=(lane>>4)*4+reg
  const int col = lane & 15;
  const int rbase = (lane >> 4) * 4;
#pragma unroll
  for (int i = 0; i < 4; ++i) {
#pragma unroll
    for (int r = 0; r < 4; ++r) {
      const int m = m0 + wm * 64 + i * 16 + rbase + r;
#pragma unroll
      for (int j = 0; j < 2; ++j) {
        const int n = n0 + wn * 32 + j * 16 + col;
        if (n < N) {
          float cur = acc[i][j][r] + bias[n];
          cur = cur > 0.0f ? cur : 0.0f;
          const size_t idx = (size_t)m * N + n;
          const float mo = mem[idx];
          const float reset = (mo - 1.0f > 0.0f) ? 1.0f : 0.0f;
          float mn = __fmul_rn(0.95f, mo);
          mn = __fadd_rn(mn, cur);
          mn = __fsub_rn(mn, reset);
          mem[idx] = mn;
          const float s = (mn - 1.0f > 0.0f) ? 1.0f : 0.0f;
          if (mode == 1) {
            sr[idx] = s;
            mr[idx] = tanhf(mn);
          } else {
            spk[idx] = __float2bfloat16(s);
          }
        }
      }
    }
  }
}

// ---------------------------------------------------------------------------
extern "C" void kernel_launch(void* const* d_in, const int* in_sizes, int n_in,
                              void* d_out, int out_size, void* d_ws,
                              size_t ws_size, hipStream_t stream) {
  const float* x = (const float*)d_in[0];
  const float* W[5];
  const float* bi[5];
  for (int i = 0; i < 5; ++i) {
    W[i] = (const float*)d_in[1 + 2 * i];
    bi[i] = (const float*)d_in[2 + 2 * i];
  }

  const int B = B_TOTAL;
  const int Ns[5] = {128, 256, 512, 1024, 784};
  const int Ks[5] = {100, 128, 256, 512, 1024};

  char* ws = (char*)d_ws;
  size_t off = 0;
  auto alloc = [&](size_t bytes) {
    void* p = ws + off;
    off = (off + bytes + 255) & ~(size_t)255;
    return p;
  };

  float* mem[5];
  for (int i = 0; i < 5; ++i) mem[i] = (float*)alloc((size_t)B * Ns[i] * 4);
  const size_t memBytes = off;
  float* cur1 = (float*)alloc((size_t)B * 128 * 4);
  bf16* s1[2], *s2[2], *s3[2], *s4[2];
  for (int p = 0; p < 2; ++p) {
    s1[p] = (bf16*)alloc((size_t)B * 128 * 2);
    s2[p] = (bf16*)alloc((size_t)B * 256 * 2);
    s3[p] = (bf16*)alloc((size_t)B * 512 * 2);
    s4[p] = (bf16*)alloc((size_t)B * 1024 * 2);
  }
  bf16* Wc[5];
  for (int i = 1; i < 5; ++i)
    Wc[i] = (bf16*)alloc((size_t)Ns[i] * Ks[i] * 3 * 2);

  hipMemsetAsync(d_ws, 0, memBytes, stream);

  float* outF = (float*)d_out;
  float* spk_rec = outF;
  float* mem_rec = outF + (size_t)25 * B * 784;

  // triple-split weights for layers 2..5
  for (int i = 1; i < 5; ++i) {
    const int total = Ns[i] * Ks[i];
    split3_kernel<<<(total + 255) / 256, 256, 0, stream>>>(W[i], Wc[i], total,
                                                           Ks[i]);
  }

  // layer-1 current: relu(x @ W1^T + b1), computed once (x is step-invariant)
  gemm_relu_f32_kernel<<<dim3(2, B / 64), 256, 0, stream>>>(x, W[0], bi[0],
                                                            cur1, 128, 100);

  for (int d = 0; d <= 28; ++d) {
    const int n5 = (d >= 4) ? 208 : 0;
    const int n4 = (d >= 3 && d <= 27) ? 256 : 0;
    const int n3 = (d >= 2 && d <= 26) ? 128 : 0;
    const int n2 = (d >= 1 && d <= 25) ? 64 : 0;
    const int n1 = (d <= 24) ? 256 : 0;
    const int total = n5 + n4 + n3 + n2 + n1;
    const int p = d & 1, q = p ^ 1;
    const int step5 = (d >= 4) ? (d - 4) : 0;
    diag_kernel<<<total, 256, 0, stream>>>(
        d,
        cur1, mem[0], s1[p],
        s1[q], Wc[1], bi[1], mem[1], s2[p],
        s2[q], Wc[2], bi[2], mem[2], s3[p],
        s3[q], Wc[3], bi[3], mem[3], s4[p],
        s4[q], Wc[4], bi[4], mem[4],
        spk_rec + (size_t)step5 * B * 784, mem_rec + (size_t)step5 * B * 784);
  }
}

// Round 6
// 2014.154 us; speedup vs baseline: 4.0118x; 1.2820x over previous
//
#include <hip/hip_runtime.h>
#include <hip/hip_bf16.h>
#include <math.h>

// SNN: 5 LIF layers, B=2048, dims 100->128->256->512->1024->784, 25 steps.
// Round 6: f16 TWO-way split (vs round 4/5's bf16 triple split): w*64 =
// hi + lo*2^-12 with residual <= 2^-23|w| -- same exactness class, 2/3 the
// MFMA work. Denorm hazards removed by exact power-of-2 scalings: weights
// pre-scaled x64 (epilogue multiplies acc by 2^-6, exact), lo stored x2^12
// and lo-phase spikes fed as 2^-12 (product exactly lo). Spikes {0,1,2^-12}
// are exact in f16. Everything else (diagonal fusion, tiles, LIF op order)
// is round-5 verbatim.

typedef __hip_bfloat16 bf16;
typedef _Float16 f16;
typedef __attribute__((ext_vector_type(8))) short short8;
typedef __attribute__((ext_vector_type(8))) _Float16 half8;
typedef __attribute__((ext_vector_type(4))) float f32x4;

#define B_TOTAL 2048
#define LO_SPIKE 2.44140625e-4f  // 2^-12, exact in f16
#define ACC_SCALE 0.015625f      // 2^-6, undoes the x64 weight pre-scale

// ---------- fp32 64x64 GEMM + relu (layer-1 current, runs once) ------------
__global__ __launch_bounds__(256) void gemm_relu_f32_kernel(
    const float* __restrict__ h, const float* __restrict__ W,
    const float* __restrict__ bias, float* __restrict__ out, int N, int K) {
  __shared__ float As[16][64];
  __shared__ float Bs[16][64];

  const int t = threadIdx.x;
  const int tx = t & 15;
  const int ty = t >> 4;
  const int m0 = blockIdx.y * 64;
  const int n0 = blockIdx.x * 64;
  const int lr = t >> 2;
  const int lc = (t & 3) * 4;

  float acc[4][4];
#pragma unroll
  for (int i = 0; i < 4; ++i)
#pragma unroll
    for (int j = 0; j < 4; ++j) acc[i][j] = 0.0f;

  const int ktiles = (K + 15) / 16;
  for (int kt = 0; kt < ktiles; ++kt) {
    const int kbase = kt * 16;
    {
      const float* src = h + (size_t)(m0 + lr) * K + kbase + lc;
#pragma unroll
      for (int j = 0; j < 4; ++j) {
        const int kg = kbase + lc + j;
        As[lc + j][lr] = (kg < K) ? src[j] : 0.0f;
      }
    }
    {
      const int nr = n0 + lr;
      const float* src = W + (size_t)nr * K + kbase + lc;
#pragma unroll
      for (int j = 0; j < 4; ++j) {
        const int kg = kbase + lc + j;
        Bs[lc + j][lr] = (nr < N && kg < K) ? src[j] : 0.0f;
      }
    }
    __syncthreads();
#pragma unroll
    for (int k = 0; k < 16; ++k) {
      float a[4], bb[4];
#pragma unroll
      for (int i = 0; i < 4; ++i) a[i] = As[k][ty * 4 + i];
#pragma unroll
      for (int j = 0; j < 4; ++j) bb[j] = Bs[k][tx * 4 + j];
#pragma unroll
      for (int i = 0; i < 4; ++i)
#pragma unroll
        for (int j = 0; j < 4; ++j) acc[i][j] = fmaf(a[i], bb[j], acc[i][j]);
    }
    __syncthreads();
  }

#pragma unroll
  for (int i = 0; i < 4; ++i) {
    const int m = m0 + ty * 4 + i;
#pragma unroll
    for (int j = 0; j < 4; ++j) {
      const int n = n0 + tx * 4 + j;
      if (n < N) {
        float cur = acc[i][j] + bias[n];
        out[(size_t)m * N + n] = cur > 0.0f ? cur : 0.0f;
      }
    }
  }
}

// ---------- f16 2-split: W fp32 [N,K] -> Wc f16 [N, 2K] = [hi | lo*2^12] ---
// w64 = w*64 (exact). hi = RN_f16(w64); r = w64 - hi (exact fp32);
// lo' = RN_f16(r * 2^12) (scale exact). GEMM contribution:
// 1.0*hi + 2^-12*lo' = w64 + eps, |eps| <= 2^-23 |w64|. Epilogue *2^-6 exact.
__global__ __launch_bounds__(256) void split2_kernel(
    const float* __restrict__ W, f16* __restrict__ Wc, int total, int K) {
  const int idx = blockIdx.x * 256 + threadIdx.x;
  if (idx < total) {
    const int n = idx / K;
    const int k = idx - n * K;
    const float w64 = W[idx] * 64.0f;
    const f16 hi = (f16)w64;
    const float r = w64 - (float)hi;
    const f16 lo = (f16)(r * 4096.0f);
    const size_t base = (size_t)n * 2 * K + k;
    Wc[base] = hi;
    Wc[base + K] = lo;
  }
}

// ---------- fused diagonal kernel ------------------------------------------
// Block ranges (longest task first):
//   L5 gemm (step d-4): 208 blocks   active d in [4,28]
//   L4 gemm (step d-3): 256 blocks   active d in [3,27]
//   L3 gemm (step d-2): 128 blocks   active d in [2,26]
//   L2 gemm (step d-1):  64 blocks   active d in [1,25]
//   lif1    (step d  ): 256 blocks   active d in [0,24]
// Spike buffers double-buffered by diagonal parity. Each producer writes two
// spike arrays: s (1.0/0.0) for the hi phase and ss (2^-12/0.0) for the lo
// phase of the consumer's split GEMM.
__global__ __launch_bounds__(256) void diag_kernel(
    int d,
    // lif1
    const float* __restrict__ cur1, float* __restrict__ mem1,
    f16* __restrict__ s1_out, f16* __restrict__ s1s_out,
    // L2
    const f16* __restrict__ s1_in, const f16* __restrict__ s1s_in,
    const f16* __restrict__ Wc2, const float* __restrict__ b2,
    float* __restrict__ mem2, f16* __restrict__ s2_out,
    f16* __restrict__ s2s_out,
    // L3
    const f16* __restrict__ s2_in, const f16* __restrict__ s2s_in,
    const f16* __restrict__ Wc3, const float* __restrict__ b3,
    float* __restrict__ mem3, f16* __restrict__ s3_out,
    f16* __restrict__ s3s_out,
    // L4
    const f16* __restrict__ s3_in, const f16* __restrict__ s3s_in,
    const f16* __restrict__ Wc4, const float* __restrict__ b4,
    float* __restrict__ mem4, f16* __restrict__ s4_out,
    f16* __restrict__ s4s_out,
    // L5
    const f16* __restrict__ s4_in, const f16* __restrict__ s4s_in,
    const f16* __restrict__ Wc5, const float* __restrict__ b5,
    float* __restrict__ mem5, float* __restrict__ sr,
    float* __restrict__ mr) {
  __shared__ f16 As[128][72];  // +8 pad: 2-way bank aliasing only (free)
  __shared__ f16 Bs[64][72];

  const int n5 = (d >= 4) ? 208 : 0;  // d <= 28 by construction
  const int n4 = (d >= 3 && d <= 27) ? 256 : 0;
  const int n3 = (d >= 2 && d <= 26) ? 128 : 0;
  const int n2 = (d >= 1 && d <= 25) ? 64 : 0;

  int b = blockIdx.x;
  const f16* Aone;
  const f16* Asml;
  const f16* Wc;
  const float* bias;
  float* mem;
  f16* spk = nullptr;
  f16* spks = nullptr;
  int N, K, nbx, mode, lb;

  if (b < n5) {
    lb = b; Aone = s4_in; Asml = s4s_in; Wc = Wc5; bias = b5; mem = mem5;
    N = 784; K = 1024; nbx = 13; mode = 1;
  } else if ((b -= n5) < n4) {
    lb = b; Aone = s3_in; Asml = s3s_in; Wc = Wc4; bias = b4; mem = mem4;
    spk = s4_out; spks = s4s_out;
    N = 1024; K = 512; nbx = 16; mode = 0;
  } else if ((b -= n4) < n3) {
    lb = b; Aone = s2_in; Asml = s2s_in; Wc = Wc3; bias = b3; mem = mem3;
    spk = s3_out; spks = s3s_out;
    N = 512; K = 256; nbx = 8; mode = 0;
  } else if ((b -= n3) < n2) {
    lb = b; Aone = s1_in; Asml = s1s_in; Wc = Wc2; bias = b2; mem = mem2;
    spk = s2_out; spks = s2s_out;
    N = 256; K = 128; nbx = 4; mode = 0;
  } else {
    // ---- lif1 task: 256 blocks x 256 threads x 4 elems = 2048*128 ----
    lb = b - n2;
    const int i0 = (lb * 256 + (int)threadIdx.x) * 4;
    const float4 c = *(const float4*)(cur1 + i0);
    const float4 mo4 = *(const float4*)(mem1 + i0);
    const float c_a[4] = {c.x, c.y, c.z, c.w};
    const float mo_a[4] = {mo4.x, mo4.y, mo4.z, mo4.w};
    float mn_a[4];
#pragma unroll
    for (int j = 0; j < 4; ++j) {
      const float mo = mo_a[j];
      const float reset = (mo - 1.0f > 0.0f) ? 1.0f : 0.0f;
      float mn = __fmul_rn(0.95f, mo);
      mn = __fadd_rn(mn, c_a[j]);
      mn = __fsub_rn(mn, reset);
      mn_a[j] = mn;
      const float s = (mn - 1.0f > 0.0f) ? 1.0f : 0.0f;
      s1_out[i0 + j] = (f16)s;
      s1s_out[i0 + j] = (f16)(s * LO_SPIKE);
    }
    float4 mv;
    mv.x = mn_a[0]; mv.y = mn_a[1]; mv.z = mn_a[2]; mv.w = mn_a[3];
    *(float4*)(mem1 + i0) = mv;
    return;
  }

  // ---- GEMM + LIF task: hi phase (A=1.0 spikes) then lo phase (A=2^-12) ---
  const int K2 = 2 * K;
  const int t = threadIdx.x;
  const int lane = t & 63;
  const int w = t >> 6;
  const int wm = w >> 1;
  const int wn = w & 1;
  const int m0 = (lb / nbx) * 128;
  const int n0 = (lb % nbx) * 64;

  const int lrow = t >> 3;
  const int lk = (t & 7) * 8;

  f32x4 acc[4][2];
#pragma unroll
  for (int i = 0; i < 4; ++i)
#pragma unroll
    for (int j = 0; j < 2; ++j) acc[i][j] = 0.0f;

  for (int kt = 0; kt < K2; kt += 64) {
    const f16* Asrc = (kt < K) ? Aone : Asml;
    const int ka = (kt < K) ? kt : (kt - K);
    {
      const f16* srcA = Asrc + (size_t)(m0 + lrow) * K + ka + lk;
#pragma unroll
      for (int i = 0; i < 4; ++i)
        *(short8*)(&As[lrow + 32 * i][lk]) =
            *(const short8*)(srcA + (size_t)32 * i * K);
    }
    {
#pragma unroll
      for (int i = 0; i < 2; ++i) {
        const int r = lrow + 32 * i;
        short8 vb = {};
        if (n0 + r < N)
          vb = *(const short8*)(Wc + (size_t)(n0 + r) * K2 + kt + lk);
        *(short8*)(&Bs[r][lk]) = vb;
      }
    }
    __syncthreads();
#pragma unroll
    for (int ks = 0; ks < 64; ks += 32) {
      const int kb = ks + (lane >> 4) * 8;
      half8 af[4], bfr[2];
#pragma unroll
      for (int i = 0; i < 4; ++i)
        af[i] = *(const half8*)(&As[wm * 64 + i * 16 + (lane & 15)][kb]);
#pragma unroll
      for (int j = 0; j < 2; ++j)
        bfr[j] = *(const half8*)(&Bs[wn * 32 + j * 16 + (lane & 15)][kb]);
#pragma unroll
      for (int i = 0; i < 4; ++i)
#pragma unroll
        for (int j = 0; j < 2; ++j)
          acc[i][j] = __builtin_amdgcn_mfma_f32_16x16x32_f16(
              af[i], bfr[j], acc[i][j], 0, 0, 0);
    }
    __syncthreads();
  }

  // epilogue: C/D mapping col=lane&15, row=(lane>>4)*4+reg
  const int col = lane & 15;
  const int rbase = (lane >> 4) * 4;
#pragma unroll
  for (int i = 0; i < 4; ++i) {
#pragma unroll
    for (int r = 0; r < 4; ++r) {
      const int m = m0 + wm * 64 + i * 16 + rbase + r;
#pragma unroll
      for (int j = 0; j < 2; ++j) {
        const int n = n0 + wn * 32 + j * 16 + col;
        if (n < N) {
          // acc*2^-6 is exact; the +bias is the single rounding (as before)
          float cur = __fadd_rn(__fmul_rn(acc[i][j][r], ACC_SCALE), bias[n]);
          cur = cur > 0.0f ? cur : 0.0f;
          const size_t idx = (size_t)m * N + n;
          const float mo = mem[idx];
          const float reset = (mo - 1.0f > 0.0f) ? 1.0f : 0.0f;
          float mn = __fmul_rn(0.95f, mo);
          mn = __fadd_rn(mn, cur);
          mn = __fsub_rn(mn, reset);
          mem[idx] = mn;
          const float s = (mn - 1.0f > 0.0f) ? 1.0f : 0.0f;
          if (mode == 1) {
            sr[idx] = s;
            mr[idx] = tanhf(mn);
          } else {
            spk[idx] = (f16)s;
            spks[idx] = (f16)(s * LO_SPIKE);
          }
        }
      }
    }
  }
}

// ---------------------------------------------------------------------------
extern "C" void kernel_launch(void* const* d_in, const int* in_sizes, int n_in,
                              void* d_out, int out_size, void* d_ws,
                              size_t ws_size, hipStream_t stream) {
  const float* x = (const float*)d_in[0];
  const float* W[5];
  const float* bi[5];
  for (int i = 0; i < 5; ++i) {
    W[i] = (const float*)d_in[1 + 2 * i];
    bi[i] = (const float*)d_in[2 + 2 * i];
  }

  const int B = B_TOTAL;
  const int Ns[5] = {128, 256, 512, 1024, 784};
  const int Ks[5] = {100, 128, 256, 512, 1024};

  char* ws = (char*)d_ws;
  size_t off = 0;
  auto alloc = [&](size_t bytes) {
    void* p = ws + off;
    off = (off + bytes + 255) & ~(size_t)255;
    return p;
  };

  float* mem[5];
  for (int i = 0; i < 5; ++i) mem[i] = (float*)alloc((size_t)B * Ns[i] * 4);
  const size_t memBytes = off;
  float* cur1 = (float*)alloc((size_t)B * 128 * 4);
  f16 *s1[2], *s2[2], *s3[2], *s4[2];
  f16 *s1s[2], *s2s[2], *s3s[2], *s4s[2];
  for (int p = 0; p < 2; ++p) {
    s1[p] = (f16*)alloc((size_t)B * 128 * 2);
    s1s[p] = (f16*)alloc((size_t)B * 128 * 2);
    s2[p] = (f16*)alloc((size_t)B * 256 * 2);
    s2s[p] = (f16*)alloc((size_t)B * 256 * 2);
    s3[p] = (f16*)alloc((size_t)B * 512 * 2);
    s3s[p] = (f16*)alloc((size_t)B * 512 * 2);
    s4[p] = (f16*)alloc((size_t)B * 1024 * 2);
    s4s[p] = (f16*)alloc((size_t)B * 1024 * 2);
  }
  f16* Wc[5];
  for (int i = 1; i < 5; ++i)
    Wc[i] = (f16*)alloc((size_t)Ns[i] * Ks[i] * 2 * 2);

  hipMemsetAsync(d_ws, 0, memBytes, stream);

  float* outF = (float*)d_out;
  float* spk_rec = outF;
  float* mem_rec = outF + (size_t)25 * B * 784;

  // 2-split weights for layers 2..5
  for (int i = 1; i < 5; ++i) {
    const int total = Ns[i] * Ks[i];
    split2_kernel<<<(total + 255) / 256, 256, 0, stream>>>(W[i], Wc[i], total,
                                                           Ks[i]);
  }

  // layer-1 current: relu(x @ W1^T + b1), computed once (x is step-invariant)
  gemm_relu_f32_kernel<<<dim3(2, B / 64), 256, 0, stream>>>(x, W[0], bi[0],
                                                            cur1, 128, 100);

  for (int d = 0; d <= 28; ++d) {
    const int n5 = (d >= 4) ? 208 : 0;
    const int n4 = (d >= 3 && d <= 27) ? 256 : 0;
    const int n3 = (d >= 2 && d <= 26) ? 128 : 0;
    const int n2 = (d >= 1 && d <= 25) ? 64 : 0;
    const int n1 = (d <= 24) ? 256 : 0;
    const int total = n5 + n4 + n3 + n2 + n1;
    const int p = d & 1, q = p ^ 1;
    const int step5 = (d >= 4) ? (d - 4) : 0;
    diag_kernel<<<total, 256, 0, stream>>>(
        d,
        cur1, mem[0], s1[p], s1s[p],
        s1[q], s1s[q], Wc[1], bi[1], mem[1], s2[p], s2s[p],
        s2[q], s2s[q], Wc[2], bi[2], mem[2], s3[p], s3s[p],
        s3[q], s3s[q], Wc[3], bi[3], mem[3], s4[p], s4s[p],
        s4[q], s4s[q], Wc[4], bi[4], mem[4],
        spk_rec + (size_t)step5 * B * 784, mem_rec + (size_t)step5 * B * 784);
  }
}

// Round 7
// 1789.706 us; speedup vs baseline: 4.5149x; 1.1254x over previous
//
#include <hip/hip_runtime.h>
#include <hip/hip_bf16.h>
#include <math.h>

// SNN: 5 LIF layers, B=2048, dims 100->128->256->512->1024->784, 25 steps.
// Round 7: fused hi/lo split pass with dual accumulators + A-fragments loaded
// DIRECTLY from global (L1/L2) instead of LDS. LDS now holds only B (hi+lo,
// 18 KB), cutting LDS traffic per K-64 tile from 72 KB to 48 KB and the
// A-tile staging entirely; MFMA becomes the longest pole. Epilogue combines
// (acc_hi + 2^-12*acc_lo)*2^-6 -- both scalings exact, one extra fp32 add
// (reorder-class error, same family as rounds 3-6 which all passed).
// Spikes are plain {0,1} f16 (the 2^-12 spike arrays are gone).

typedef __hip_bfloat16 bf16;
typedef _Float16 f16;
typedef __attribute__((ext_vector_type(8))) short short8;
typedef __attribute__((ext_vector_type(8))) _Float16 half8;
typedef __attribute__((ext_vector_type(4))) float f32x4;

#define B_TOTAL 2048
#define LO_SCALE 2.44140625e-4f  // 2^-12, undoes the lo x2^12 storage scale
#define ACC_SCALE 0.015625f      // 2^-6, undoes the x64 weight pre-scale

// ---------- fp32 64x64 GEMM + relu (layer-1 current, runs once) ------------
__global__ __launch_bounds__(256) void gemm_relu_f32_kernel(
    const float* __restrict__ h, const float* __restrict__ W,
    const float* __restrict__ bias, float* __restrict__ out, int N, int K) {
  __shared__ float As[16][64];
  __shared__ float Bs[16][64];

  const int t = threadIdx.x;
  const int tx = t & 15;
  const int ty = t >> 4;
  const int m0 = blockIdx.y * 64;
  const int n0 = blockIdx.x * 64;
  const int lr = t >> 2;
  const int lc = (t & 3) * 4;

  float acc[4][4];
#pragma unroll
  for (int i = 0; i < 4; ++i)
#pragma unroll
    for (int j = 0; j < 4; ++j) acc[i][j] = 0.0f;

  const int ktiles = (K + 15) / 16;
  for (int kt = 0; kt < ktiles; ++kt) {
    const int kbase = kt * 16;
    {
      const float* src = h + (size_t)(m0 + lr) * K + kbase + lc;
#pragma unroll
      for (int j = 0; j < 4; ++j) {
        const int kg = kbase + lc + j;
        As[lc + j][lr] = (kg < K) ? src[j] : 0.0f;
      }
    }
    {
      const int nr = n0 + lr;
      const float* src = W + (size_t)nr * K + kbase + lc;
#pragma unroll
      for (int j = 0; j < 4; ++j) {
        const int kg = kbase + lc + j;
        Bs[lc + j][lr] = (nr < N && kg < K) ? src[j] : 0.0f;
      }
    }
    __syncthreads();
#pragma unroll
    for (int k = 0; k < 16; ++k) {
      float a[4], bb[4];
#pragma unroll
      for (int i = 0; i < 4; ++i) a[i] = As[k][ty * 4 + i];
#pragma unroll
      for (int j = 0; j < 4; ++j) bb[j] = Bs[k][tx * 4 + j];
#pragma unroll
      for (int i = 0; i < 4; ++i)
#pragma unroll
        for (int j = 0; j < 4; ++j) acc[i][j] = fmaf(a[i], bb[j], acc[i][j]);
    }
    __syncthreads();
  }

#pragma unroll
  for (int i = 0; i < 4; ++i) {
    const int m = m0 + ty * 4 + i;
#pragma unroll
    for (int j = 0; j < 4; ++j) {
      const int n = n0 + tx * 4 + j;
      if (n < N) {
        float cur = acc[i][j] + bias[n];
        out[(size_t)m * N + n] = cur > 0.0f ? cur : 0.0f;
      }
    }
  }
}

// ---------- f16 2-split: W fp32 [N,K] -> Wc f16 [N, 2K] = [hi | lo*2^12] ---
__global__ __launch_bounds__(256) void split2_kernel(
    const float* __restrict__ W, f16* __restrict__ Wc, int total, int K) {
  const int idx = blockIdx.x * 256 + threadIdx.x;
  if (idx < total) {
    const int n = idx / K;
    const int k = idx - n * K;
    const float w64 = W[idx] * 64.0f;
    const f16 hi = (f16)w64;
    const float r = w64 - (float)hi;
    const f16 lo = (f16)(r * 4096.0f);
    const size_t base = (size_t)n * 2 * K + k;
    Wc[base] = hi;
    Wc[base + K] = lo;
  }
}

// ---------- fused diagonal kernel ------------------------------------------
// Block ranges (longest task first):
//   L5 gemm (step d-4): 208 blocks   active d in [4,28]
//   L4 gemm (step d-3): 256 blocks   active d in [3,27]
//   L3 gemm (step d-2): 128 blocks   active d in [2,26]
//   L2 gemm (step d-1):  64 blocks   active d in [1,25]
//   lif1    (step d  ): 256 blocks   active d in [0,24]
// Spike buffers double-buffered by diagonal parity.
__global__ __launch_bounds__(256) void diag_kernel(
    int d,
    // lif1
    const float* __restrict__ cur1, float* __restrict__ mem1,
    f16* __restrict__ s1_out,
    // L2
    const f16* __restrict__ s1_in, const f16* __restrict__ Wc2,
    const float* __restrict__ b2, float* __restrict__ mem2,
    f16* __restrict__ s2_out,
    // L3
    const f16* __restrict__ s2_in, const f16* __restrict__ Wc3,
    const float* __restrict__ b3, float* __restrict__ mem3,
    f16* __restrict__ s3_out,
    // L4
    const f16* __restrict__ s3_in, const f16* __restrict__ Wc4,
    const float* __restrict__ b4, float* __restrict__ mem4,
    f16* __restrict__ s4_out,
    // L5
    const f16* __restrict__ s4_in, const f16* __restrict__ Wc5,
    const float* __restrict__ b5, float* __restrict__ mem5,
    float* __restrict__ sr, float* __restrict__ mr) {
  // B tile only: rows 0..63 = hi, rows 64..127 = lo. +8 pad (2-way: free).
  __shared__ f16 Bs[128][72];

  const int n5 = (d >= 4) ? 208 : 0;  // d <= 28 by construction
  const int n4 = (d >= 3 && d <= 27) ? 256 : 0;
  const int n3 = (d >= 2 && d <= 26) ? 128 : 0;
  const int n2 = (d >= 1 && d <= 25) ? 64 : 0;

  int b = blockIdx.x;
  const f16* A;
  const f16* Wc;
  const float* bias;
  float* mem;
  f16* spk = nullptr;
  int N, K, nbx, mode, lb;

  if (b < n5) {
    lb = b; A = s4_in; Wc = Wc5; bias = b5; mem = mem5;
    N = 784; K = 1024; nbx = 13; mode = 1;
  } else if ((b -= n5) < n4) {
    lb = b; A = s3_in; Wc = Wc4; bias = b4; mem = mem4; spk = s4_out;
    N = 1024; K = 512; nbx = 16; mode = 0;
  } else if ((b -= n4) < n3) {
    lb = b; A = s2_in; Wc = Wc3; bias = b3; mem = mem3; spk = s3_out;
    N = 512; K = 256; nbx = 8; mode = 0;
  } else if ((b -= n3) < n2) {
    lb = b; A = s1_in; Wc = Wc2; bias = b2; mem = mem2; spk = s2_out;
    N = 256; K = 128; nbx = 4; mode = 0;
  } else {
    // ---- lif1 task: 256 blocks x 256 threads x 4 elems = 2048*128 ----
    lb = b - n2;
    const int i0 = (lb * 256 + (int)threadIdx.x) * 4;
    const float4 c = *(const float4*)(cur1 + i0);
    const float4 mo4 = *(const float4*)(mem1 + i0);
    const float c_a[4] = {c.x, c.y, c.z, c.w};
    const float mo_a[4] = {mo4.x, mo4.y, mo4.z, mo4.w};
    float mn_a[4];
#pragma unroll
    for (int j = 0; j < 4; ++j) {
      const float mo = mo_a[j];
      const float reset = (mo - 1.0f > 0.0f) ? 1.0f : 0.0f;
      float mn = __fmul_rn(0.95f, mo);
      mn = __fadd_rn(mn, c_a[j]);
      mn = __fsub_rn(mn, reset);
      mn_a[j] = mn;
      s1_out[i0 + j] = (f16)((mn - 1.0f > 0.0f) ? 1.0f : 0.0f);
    }
    float4 mv;
    mv.x = mn_a[0]; mv.y = mn_a[1]; mv.z = mn_a[2]; mv.w = mn_a[3];
    *(float4*)(mem1 + i0) = mv;
    return;
  }

  // ---- GEMM + LIF: single pass over K, dual accumulators (hi & lo) ----
  const int K2 = 2 * K;
  const int t = threadIdx.x;
  const int lane = t & 63;
  const int w = t >> 6;
  const int wm = w >> 1;
  const int wn = w & 1;
  const int m0 = (lb / nbx) * 128;
  const int n0 = (lb % nbx) * 64;

  const int lrow = t >> 3;     // 0..31
  const int lk = (t & 7) * 8;  // 0,8,...,56

  f32x4 acch[4][2], accl[4][2];
#pragma unroll
  for (int i = 0; i < 4; ++i)
#pragma unroll
    for (int j = 0; j < 2; ++j) { acch[i][j] = 0.0f; accl[i][j] = 0.0f; }

  // per-lane A base: row m0 + wm*64 + (lane&15), plus i*16 rows inside loop
  const f16* Abase = A + (size_t)(m0 + wm * 64 + (lane & 15)) * K +
                     ((lane >> 4) * 8);

  for (int kt = 0; kt < K; kt += 64) {
    // stage B hi+lo (each thread: 2 rows x 8 f16 per half)
    {
#pragma unroll
      for (int i = 0; i < 2; ++i) {
        const int r = lrow + 32 * i;
        const int nr = n0 + r;
        short8 vh = {}, vl = {};
        if (nr < N) {
          const f16* src = Wc + (size_t)nr * K2 + kt + lk;
          vh = *(const short8*)(src);
          vl = *(const short8*)(src + K);
        }
        *(short8*)(&Bs[r][lk]) = vh;
        *(short8*)(&Bs[64 + r][lk]) = vl;
      }
    }
    __syncthreads();
#pragma unroll
    for (int ks = 0; ks < 64; ks += 32) {
      const int kb = ks + (lane >> 4) * 8;
      half8 af[4], bh[2], bl[2];
      // A fragments direct from global (L1/L2-resident, perfectly coalesced:
      // lanes {i,i+16,i+32,i+48} cover one 64B line)
#pragma unroll
      for (int i = 0; i < 4; ++i)
        af[i] = *(const half8*)(Abase + (size_t)i * 16 * K + kt + ks);
#pragma unroll
      for (int j = 0; j < 2; ++j) {
        bh[j] = *(const half8*)(&Bs[wn * 32 + j * 16 + (lane & 15)][kb]);
        bl[j] = *(const half8*)(&Bs[64 + wn * 32 + j * 16 + (lane & 15)][kb]);
      }
#pragma unroll
      for (int i = 0; i < 4; ++i)
#pragma unroll
        for (int j = 0; j < 2; ++j) {
          acch[i][j] = __builtin_amdgcn_mfma_f32_16x16x32_f16(
              af[i], bh[j], acch[i][j], 0, 0, 0);
          accl[i][j] = __builtin_amdgcn_mfma_f32_16x16x32_f16(
              af[i], bl[j], accl[i][j], 0, 0, 0);
        }
    }
    __syncthreads();
  }

  // epilogue: C/D mapping col=lane&15, row=(lane>>4)*4+reg
  const int col = lane & 15;
  const int rbase = (lane >> 4) * 4;
#pragma unroll
  for (int i = 0; i < 4; ++i) {
#pragma unroll
    for (int r = 0; r < 4; ++r) {
      const int m = m0 + wm * 64 + i * 16 + rbase + r;
#pragma unroll
      for (int j = 0; j < 2; ++j) {
        const int n = n0 + wn * 32 + j * 16 + col;
        if (n < N) {
          // (acc_hi + acc_lo*2^-12)*2^-6 + bias; both scalings exact
          const float v =
              __fadd_rn(acch[i][j][r], __fmul_rn(accl[i][j][r], LO_SCALE));
          float cur = __fadd_rn(__fmul_rn(v, ACC_SCALE), bias[n]);
          cur = cur > 0.0f ? cur : 0.0f;
          const size_t idx = (size_t)m * N + n;
          const float mo = mem[idx];
          const float reset = (mo - 1.0f > 0.0f) ? 1.0f : 0.0f;
          float mn = __fmul_rn(0.95f, mo);
          mn = __fadd_rn(mn, cur);
          mn = __fsub_rn(mn, reset);
          mem[idx] = mn;
          const float s = (mn - 1.0f > 0.0f) ? 1.0f : 0.0f;
          if (mode == 1) {
            sr[idx] = s;
            mr[idx] = tanhf(mn);
          } else {
            spk[idx] = (f16)s;
          }
        }
      }
    }
  }
}

// ---------------------------------------------------------------------------
extern "C" void kernel_launch(void* const* d_in, const int* in_sizes, int n_in,
                              void* d_out, int out_size, void* d_ws,
                              size_t ws_size, hipStream_t stream) {
  const float* x = (const float*)d_in[0];
  const float* W[5];
  const float* bi[5];
  for (int i = 0; i < 5; ++i) {
    W[i] = (const float*)d_in[1 + 2 * i];
    bi[i] = (const float*)d_in[2 + 2 * i];
  }

  const int B = B_TOTAL;
  const int Ns[5] = {128, 256, 512, 1024, 784};
  const int Ks[5] = {100, 128, 256, 512, 1024};

  char* ws = (char*)d_ws;
  size_t off = 0;
  auto alloc = [&](size_t bytes) {
    void* p = ws + off;
    off = (off + bytes + 255) & ~(size_t)255;
    return p;
  };

  float* mem[5];
  for (int i = 0; i < 5; ++i) mem[i] = (float*)alloc((size_t)B * Ns[i] * 4);
  const size_t memBytes = off;
  float* cur1 = (float*)alloc((size_t)B * 128 * 4);
  f16 *s1[2], *s2[2], *s3[2], *s4[2];
  for (int p = 0; p < 2; ++p) {
    s1[p] = (f16*)alloc((size_t)B * 128 * 2);
    s2[p] = (f16*)alloc((size_t)B * 256 * 2);
    s3[p] = (f16*)alloc((size_t)B * 512 * 2);
    s4[p] = (f16*)alloc((size_t)B * 1024 * 2);
  }
  f16* Wc[5];
  for (int i = 1; i < 5; ++i)
    Wc[i] = (f16*)alloc((size_t)Ns[i] * Ks[i] * 2 * 2);

  hipMemsetAsync(d_ws, 0, memBytes, stream);

  float* outF = (float*)d_out;
  float* spk_rec = outF;
  float* mem_rec = outF + (size_t)25 * B * 784;

  // 2-split weights for layers 2..5
  for (int i = 1; i < 5; ++i) {
    const int total = Ns[i] * Ks[i];
    split2_kernel<<<(total + 255) / 256, 256, 0, stream>>>(W[i], Wc[i], total,
                                                           Ks[i]);
  }

  // layer-1 current: relu(x @ W1^T + b1), computed once (x is step-invariant)
  gemm_relu_f32_kernel<<<dim3(2, B / 64), 256, 0, stream>>>(x, W[0], bi[0],
                                                            cur1, 128, 100);

  for (int d = 0; d <= 28; ++d) {
    const int n5 = (d >= 4) ? 208 : 0;
    const int n4 = (d >= 3 && d <= 27) ? 256 : 0;
    const int n3 = (d >= 2 && d <= 26) ? 128 : 0;
    const int n2 = (d >= 1 && d <= 25) ? 64 : 0;
    const int n1 = (d <= 24) ? 256 : 0;
    const int total = n5 + n4 + n3 + n2 + n1;
    const int p = d & 1, q = p ^ 1;
    const int step5 = (d >= 4) ? (d - 4) : 0;
    diag_kernel<<<total, 256, 0, stream>>>(
        d,
        cur1, mem[0], s1[p],
        s1[q], Wc[1], bi[1], mem[1], s2[p],
        s2[q], Wc[2], bi[2], mem[2], s3[p],
        s3[q], Wc[3], bi[3], mem[3], s4[p],
        s4[q], Wc[4], bi[4], mem[4],
        spk_rec + (size_t)step5 * B * 784, mem_rec + (size_t)step5 * B * 784);
  }
}